// Round 1
// baseline (362.368 us; speedup 1.0000x reference)
//
#include <hip/hip_runtime.h>
#include <cstddef>

// Problem constants
#define B 32
#define T 1024
#define J 128
#define H 1024

// ---------------------------------------------------------------------------
// k_su: s_uB[b*J+j] = dot(u[b,j,:], wu) + b0
// grid 1024 blocks x 256 threads (4 waves, 1 row per wave)
// ---------------------------------------------------------------------------
__global__ __launch_bounds__(256) void k_su(const float* __restrict__ u,
                                            const float* __restrict__ w,
                                            const float* __restrict__ bscal,
                                            float* __restrict__ suB) {
    int row = blockIdx.x * 4 + (threadIdx.x >> 6);  // b*J + j
    int lane = threadIdx.x & 63;
    const float* wu = w + H;
    const float* ur = u + (size_t)row * H;
    float acc = 0.0f;
#pragma unroll
    for (int i = 0; i < 16; ++i) {
        int d = lane + 64 * i;
        acc += ur[d] * wu[d];
    }
#pragma unroll
    for (int off = 32; off; off >>= 1) acc += __shfl_xor(acc, off);
    if (lane == 0) suB[row] = acc + bscal[0];
}

// ---------------------------------------------------------------------------
// k_gemm1: S[b, t0:t0+64, 0:128] = h @ (wh + wm*u)^T + suB
// Also writes Mrow[b,t] = max_j S[b,t,:]  (tile covers ALL j)
// grid (T/64=16, B=32), 256 threads, 8x4 microtile
// ---------------------------------------------------------------------------
__global__ __launch_bounds__(256) void k_gemm1(const float* __restrict__ h,
                                               const float* __restrict__ u,
                                               const float* __restrict__ w,
                                               const float* __restrict__ suB,
                                               float* __restrict__ S,
                                               float* __restrict__ Mrow) {
    const int b = blockIdx.y;
    const int t0 = blockIdx.x * 64;
    __shared__ float As[64][33];
    __shared__ float Bs[128][33];
    const float* wh = w;
    const float* wm = w + 2 * H;
    const int tid = threadIdx.x;
    const int kk = tid & 31, rr = tid >> 5;
    const int tx = tid & 31, ty = tid >> 5;
    float acc[8][4] = {};

    for (int k0 = 0; k0 < H; k0 += 32) {
        // stage A: h tile 64x32
#pragma unroll
        for (int p = 0; p < 8; ++p) {
            int row = rr + p * 8;
            As[row][kk] = h[((size_t)(b << 10) + t0 + row) * H + k0 + kk];
        }
        // stage B: u2 = wh + wm*u, tile 128x32
        float whk = wh[k0 + kk], wmk = wm[k0 + kk];
#pragma unroll
        for (int p = 0; p < 16; ++p) {
            int row = rr + p * 8;
            Bs[row][kk] = whk + wmk * u[((size_t)(b << 7) + row) * H + k0 + kk];
        }
        __syncthreads();
#pragma unroll
        for (int k = 0; k < 32; ++k) {
            float bv[4];
#pragma unroll
            for (int c = 0; c < 4; ++c) bv[c] = Bs[tx + 32 * c][k];
#pragma unroll
            for (int i = 0; i < 8; ++i) {
                float av = As[ty * 8 + i][k];
#pragma unroll
                for (int c = 0; c < 4; ++c) acc[i][c] += av * bv[c];
            }
        }
        __syncthreads();
    }
    // epilogue: write S, fused row-max over j (all 128 j in this tile)
#pragma unroll
    for (int i = 0; i < 8; ++i) {
        int t = t0 + ty * 8 + i;
        float mx = -INFINITY;
#pragma unroll
        for (int c = 0; c < 4; ++c) {
            int j = tx + 32 * c;
            float sv = acc[i][c] + suB[(b << 7) + j];
            S[((size_t)(b << 10) + t) * J + j] = sv;
            mx = fmaxf(mx, sv);
        }
#pragma unroll
        for (int off = 16; off; off >>= 1) mx = fmaxf(mx, __shfl_xor(mx, off, 32));
        if (tx == 0) Mrow[(b << 10) + t] = mx;
    }
}

// ---------------------------------------------------------------------------
// k_colstats_part: online (max,sum) over t-chunks of 128, per column (b,j)
// grid (J/32=4, 8 t-chunks, B=32), 256 threads = 32 j x 8 t-stride
// ---------------------------------------------------------------------------
__global__ __launch_bounds__(256) void k_colstats_part(const float* __restrict__ S,
                                                       float* __restrict__ pmax,
                                                       float* __restrict__ psum) {
    int b = blockIdx.z, j0 = blockIdx.x * 32, tc = blockIdx.y;
    int jj = threadIdx.x & 31, ts = threadIdx.x >> 5;
    int j = j0 + jj;
    float m = -INFINITY, s = 0.0f;
    for (int t = tc * 128 + ts; t < tc * 128 + 128; t += 8) {
        float v = S[((size_t)(b << 10) + t) * J + j];
        float nm = fmaxf(m, v);
        s = s * __expf(m - nm) + __expf(v - nm);
        m = nm;
    }
    __shared__ float sm[8][32], ss[8][32];
    sm[ts][jj] = m;
    ss[ts][jj] = s;
    __syncthreads();
    if (ts == 0) {
#pragma unroll
        for (int r = 1; r < 8; ++r) {
            float m2 = sm[r][jj], s2 = ss[r][jj];
            float nm = fmaxf(m, m2);
            s = s * __expf(m - nm) + s2 * __expf(m2 - nm);
            m = nm;
        }
        int col = b * J + j;
        pmax[col * 8 + tc] = m;
        psum[col * 8 + tc] = s;
    }
}

// ---------------------------------------------------------------------------
// k_colstats_red: merge the 8 partials per column
// grid 16 x 256 = 4096 columns
// ---------------------------------------------------------------------------
__global__ __launch_bounds__(256) void k_colstats_red(const float* __restrict__ pmax,
                                                      const float* __restrict__ psum,
                                                      float* __restrict__ cmax,
                                                      float* __restrict__ cinv) {
    int col = blockIdx.x * 256 + threadIdx.x;
    float m = -INFINITY, s = 0.0f;
#pragma unroll
    for (int r = 0; r < 8; ++r) {
        float m2 = pmax[col * 8 + r], s2 = psum[col * 8 + r];
        float nm = fmaxf(m, m2);
        s = s * __expf(m - nm) + s2 * __expf(m2 - nm);
        m = nm;
    }
    cmax[col] = m;
    cinv[col] = 1.0f / s;
}

// ---------------------------------------------------------------------------
// k_btstats: per batch, max over t of Mrow + sum exp -> btmax, btinv
// grid B=32 blocks x 256 threads
// ---------------------------------------------------------------------------
__global__ __launch_bounds__(256) void k_btstats(const float* __restrict__ Mrow,
                                                 float* __restrict__ btmax,
                                                 float* __restrict__ btinv) {
    int b = blockIdx.x;
    int tid = threadIdx.x;
    __shared__ float red[256];
    float m = -INFINITY;
    for (int t = tid; t < T; t += 256) m = fmaxf(m, Mrow[(b << 10) + t]);
    red[tid] = m;
    __syncthreads();
    for (int o = 128; o; o >>= 1) {
        if (tid < o) red[tid] = fmaxf(red[tid], red[tid + o]);
        __syncthreads();
    }
    m = red[0];
    __syncthreads();
    float s = 0.0f;
    for (int t = tid; t < T; t += 256) s += __expf(Mrow[(b << 10) + t] - m);
    red[tid] = s;
    __syncthreads();
    for (int o = 128; o; o >>= 1) {
        if (tid < o) red[tid] += red[tid + o];
        __syncthreads();
    }
    if (tid == 0) {
        btmax[b] = m;
        btinv[b] = 1.0f / red[0];
    }
}

// ---------------------------------------------------------------------------
// k_pnorm: P = exp(S - cmax[col]) * cinv[col], in place, float4
// grid 4096 x 256 (exact: B*T*J/4 float4s)
// ---------------------------------------------------------------------------
__global__ __launch_bounds__(256) void k_pnorm(float* __restrict__ S,
                                               const float* __restrict__ cmax,
                                               const float* __restrict__ cinv) {
    size_t idx = (size_t)blockIdx.x * 256 + threadIdx.x;
    float4 v = ((float4*)S)[idx];
    size_t e = idx * 4;
    int b = (int)(e >> 17);  // T*J = 2^17
    int j = (int)(e & 127);
    const float4 cm = *(const float4*)&cmax[b * J + j];
    const float4 ci = *(const float4*)&cinv[b * J + j];
    v.x = __expf(v.x - cm.x) * ci.x;
    v.y = __expf(v.y - cm.y) * ci.y;
    v.z = __expf(v.z - cm.z) * ci.z;
    v.w = __expf(v.w - cm.w) * ci.w;
    ((float4*)S)[idx] = v;
}

// ---------------------------------------------------------------------------
// k_q2c_part: partial q2c over t-chunks of 64
// grid (H/256=4, 16 t-chunks, B=32), 256 threads
// ---------------------------------------------------------------------------
__global__ __launch_bounds__(256) void k_q2c_part(const float* __restrict__ h,
                                                  const float* __restrict__ Mrow,
                                                  const float* __restrict__ btmax,
                                                  const float* __restrict__ btinv,
                                                  float* __restrict__ part) {
    int b = blockIdx.z, tc = blockIdx.y;
    int d = blockIdx.x * 256 + threadIdx.x;
    __shared__ float wbt[64];
    int t0 = tc * 64;
    if (threadIdx.x < 64)
        wbt[threadIdx.x] = __expf(Mrow[(b << 10) + t0 + threadIdx.x] - btmax[b]) * btinv[b];
    __syncthreads();
    float acc = 0.0f;
#pragma unroll 4
    for (int i = 0; i < 64; ++i)
        acc += wbt[i] * h[((size_t)(b << 10) + t0 + i) * H + d];
    part[((size_t)(b * 16) + tc) * H + d] = acc;
}

// ---------------------------------------------------------------------------
// k_q2c_red: q2c[b,d] = sum over 16 partials
// grid (H/256=4, B=32)
// ---------------------------------------------------------------------------
__global__ __launch_bounds__(256) void k_q2c_red(const float* __restrict__ part,
                                                 float* __restrict__ q2c) {
    int b = blockIdx.y;
    int d = blockIdx.x * 256 + threadIdx.x;
    float acc = 0.0f;
#pragma unroll
    for (int tc = 0; tc < 16; ++tc)
        acc += part[((size_t)(b * 16) + tc) * H + d];
    q2c[(b << 10) + d] = acc;
}

// ---------------------------------------------------------------------------
// k_gemm2g: c2q tile = P @ u, fused G writer (4 sections)
// grid (H/128=8, T/64=16, B=32), 256 threads, 8x4 microtile, K=J=128
// ---------------------------------------------------------------------------
__global__ __launch_bounds__(256) void k_gemm2g(const float* __restrict__ P,
                                                const float* __restrict__ u,
                                                const float* __restrict__ h,
                                                const float* __restrict__ q2c,
                                                float* __restrict__ G) {
    int b = blockIdx.z, t0 = blockIdx.y * 64, d0 = blockIdx.x * 128;
    __shared__ float Ps[64][33];
    __shared__ float Us[32][129];
    int tid = threadIdx.x;
    int tx = tid & 31, ty = tid >> 5;
    float acc[8][4] = {};

    for (int j0 = 0; j0 < J; j0 += 32) {
        int kk = tid & 31, rr = tid >> 5;
#pragma unroll
        for (int p = 0; p < 8; ++p) {
            int row = rr + p * 8;
            Ps[row][kk] = P[((size_t)(b << 10) + t0 + row) * J + j0 + kk];
        }
        int dc = tid & 127, rp = tid >> 7;
#pragma unroll
        for (int p = 0; p < 16; ++p) {
            int row = rp + p * 2;
            Us[row][dc] = u[((size_t)(b << 7) + j0 + row) * H + d0 + dc];
        }
        __syncthreads();
#pragma unroll
        for (int k = 0; k < 32; ++k) {
            float bv[4];
#pragma unroll
            for (int c = 0; c < 4; ++c) bv[c] = Us[k][tx + 32 * c];
#pragma unroll
            for (int i = 0; i < 8; ++i) {
                float av = Ps[ty * 8 + i][k];
#pragma unroll
                for (int c = 0; c < 4; ++c) acc[i][c] += av * bv[c];
            }
        }
        __syncthreads();
    }
    // epilogue: G = [h, c2q, h*c2q, h*q2c]
#pragma unroll
    for (int i = 0; i < 8; ++i) {
        int t = t0 + ty * 8 + i;
        size_t gbase = ((size_t)(b << 10) + t) * (4 * H);
        size_t hbase = ((size_t)(b << 10) + t) * H;
#pragma unroll
        for (int c = 0; c < 4; ++c) {
            int d = d0 + tx + 32 * c;
            float cv = acc[i][c];
            float hv = h[hbase + d];
            float qv = q2c[(b << 10) + d];
            G[gbase + d] = hv;
            G[gbase + H + d] = cv;
            G[gbase + 2 * H + d] = hv * cv;
            G[gbase + 3 * H + d] = hv * qv;
        }
    }
}

extern "C" void kernel_launch(void* const* d_in, const int* in_sizes, int n_in,
                              void* d_out, int out_size, void* d_ws, size_t ws_size,
                              hipStream_t stream) {
    const float* h = (const float*)d_in[0];
    const float* u = (const float*)d_in[1];
    const float* w = (const float*)d_in[2];
    const float* bb = (const float*)d_in[3];
    float* G = (float*)d_out;

    float* ws = (float*)d_ws;
    float* S = ws;                         // B*T*J = 4194304
    float* suB = S + (size_t)B * T * J;    // 4096
    float* pcm = suB + B * J;              // B*J*8 = 32768
    float* pcs = pcm + B * J * 8;          // 32768
    float* cmax = pcs + B * J * 8;         // 4096
    float* cinv = cmax + B * J;            // 4096
    float* Mrow = cinv + B * J;            // 32768
    float* btmax = Mrow + B * T;           // 32
    float* btinv = btmax + B;              // 32
    float* q2c = btinv + B;                // 32768
    float* qpart = q2c + B * H;            // B*16*H = 524288

    k_su<<<dim3(B * J / 4), 256, 0, stream>>>(u, w, bb, suB);
    k_gemm1<<<dim3(T / 64, B), 256, 0, stream>>>(h, u, w, suB, S, Mrow);
    k_colstats_part<<<dim3(J / 32, 8, B), 256, 0, stream>>>(S, pcm, pcs);
    k_colstats_red<<<dim3(B * J / 256), 256, 0, stream>>>(pcm, pcs, cmax, cinv);
    k_btstats<<<dim3(B), 256, 0, stream>>>(Mrow, btmax, btinv);
    k_pnorm<<<dim3(B * T * J / (4 * 256)), 256, 0, stream>>>(S, cmax, cinv);
    k_q2c_part<<<dim3(H / 256, 16, B), 256, 0, stream>>>(h, Mrow, btmax, btinv, qpart);
    k_q2c_red<<<dim3(H / 256, B), 256, 0, stream>>>(qpart, q2c);
    k_gemm2g<<<dim3(H / 128, T / 64, B), 256, 0, stream>>>(S, u, h, q2c, G);
}

// Round 2
// 305.441 us; speedup vs baseline: 1.1864x; 1.1864x over previous
//
#include <hip/hip_runtime.h>
#include <cstddef>
#include <cstdint>

#define B 32
#define T 1024
#define J 128
#define H 1024

typedef unsigned short ushort_t;
typedef __attribute__((ext_vector_type(8))) short bf16x8;
typedef __attribute__((ext_vector_type(4))) float f32x4;

__device__ __forceinline__ unsigned short f2bf(float f) {
    union { float f; unsigned u; } v;
    v.f = f;
    return (unsigned short)((v.u + 0x7FFFu + ((v.u >> 16) & 1u)) >> 16);
}
__device__ __forceinline__ float bf2f(unsigned short s) {
    union { unsigned u; float f; } v;
    v.u = ((unsigned)s) << 16;
    return v.f;
}

// ---------------------------------------------------------------------------
// k_su: suB[b*J+j] = dot(u[b,j,:], wu) + b0
// ---------------------------------------------------------------------------
__global__ __launch_bounds__(256) void k_su(const float* __restrict__ u,
                                            const float* __restrict__ w,
                                            const float* __restrict__ bscal,
                                            float* __restrict__ suB) {
    int row = blockIdx.x * 4 + (threadIdx.x >> 6);
    int lane = threadIdx.x & 63;
    const float* wu = w + H;
    const float* ur = u + (size_t)row * H;
    float acc = 0.0f;
#pragma unroll
    for (int i = 0; i < 16; ++i) {
        int d = lane + 64 * i;
        acc += ur[d] * wu[d];
    }
#pragma unroll
    for (int off = 32; off; off >>= 1) acc += __shfl_xor(acc, off);
    if (lane == 0) suB[row] = acc + bscal[0];
}

// ---------------------------------------------------------------------------
// k_uprep: u2_bf[b,j,d] = bf16(wh[d] + wm[d]*u), uT_bf[b,d,j] = bf16(u)
// grid (H/64, J/64, B), 256 thr; 64x64 tile transpose via LDS
// ---------------------------------------------------------------------------
__global__ __launch_bounds__(256) void k_uprep(const float* __restrict__ u,
                                               const float* __restrict__ w,
                                               ushort_t* __restrict__ u2,
                                               ushort_t* __restrict__ uT) {
    int b = blockIdx.z, j0 = blockIdx.y * 64, d0 = blockIdx.x * 64;
    __shared__ ushort_t tile[64][72];
    int tid = threadIdx.x;
    int jr = tid >> 2, c0 = (tid & 3) * 16;
    const float* wh = w;
    const float* wm = w + 2 * H;
    size_t src = ((size_t)(b << 7) + j0 + jr) * H + d0 + c0;
    union { ushort_t us[16]; uint4 v[2]; } o;
#pragma unroll
    for (int i = 0; i < 16; i += 4) {
        float4 x = *(const float4*)&u[src + i];
        const float* xp = &x.x;
#pragma unroll
        for (int k = 0; k < 4; ++k) {
            int d = d0 + c0 + i + k;
            float uu = xp[k];
            o.us[i + k] = f2bf(wh[d] + wm[d] * uu);
            tile[jr][c0 + i + k] = f2bf(uu);
        }
    }
    *(uint4*)&u2[src] = o.v[0];
    *(uint4*)&u2[src + 8] = o.v[1];
    __syncthreads();
    int dr = tid >> 2, jc0 = (tid & 3) * 16;
    union { ushort_t us[16]; uint4 v[2]; } t2;
#pragma unroll
    for (int i = 0; i < 16; ++i) t2.us[i] = tile[jc0 + i][dr];
    size_t dst = ((size_t)(b << 10) + d0 + dr) * J + j0 + jc0;
    *(uint4*)&uT[dst] = t2.v[0];
    *(uint4*)&uT[dst + 8] = t2.v[1];
}

// ---------------------------------------------------------------------------
// k_gemm1: S_bf[b,t,j] = bf16( h[b,t,:].(wh+wm*u[b,j,:]) + suB[b,j] )
// Fused: Mrow[b,t] = max_j, column partial (max,sumexp) per t-block of 128.
// MFMA 16x16x32 bf16, 128x128 tile, BK=64, 512 thr = 8 waves (4x2).
// LDS XOR swizzle: byte ^= (row&7)<<4 within 128B rows (both sides).
// ---------------------------------------------------------------------------
__global__ __launch_bounds__(512) void k_gemm1(const float* __restrict__ h,
                                               const ushort_t* __restrict__ u2,
                                               const float* __restrict__ suB,
                                               ushort_t* __restrict__ Sb,
                                               float* __restrict__ Mrow,
                                               float* __restrict__ pcm,
                                               float* __restrict__ pcs) {
    const int b = blockIdx.y;
    const int t0 = blockIdx.x * 128;
    __shared__ ushort_t As[128 * 64];
    __shared__ ushort_t Bs[128 * 64];
    __shared__ float rm_red[2][128];
    __shared__ float cm_red[4][128];
    __shared__ float cs_red[4][128];
    const int tid = threadIdx.x;
    const int lane = tid & 63, wid = tid >> 6;
    const int wr = wid >> 1, wc = wid & 1;

    f32x4 acc[2][4] = {};

    const int srow = wid * 8 + (lane >> 3);  // staging row base (0..63)
    const int su_ = lane & 7;                // 16B unit
    const int r7 = lane >> 3;                // (row & 7) for both w halves

    for (int k0 = 0; k0 < H; k0 += 64) {
        // ---- stage A: h f32 -> bf16, swizzled source-element selection
#pragma unroll
        for (int w = 0; w < 2; ++w) {
            int row = srow + w * 64;
            int kk = (su_ ^ r7) << 3;  // f32 element offset, 8 elems
            const float* src = h + ((size_t)(b << 10) + t0 + row) * H + k0 + kk;
            float4 x = *(const float4*)src;
            float4 y = *(const float4*)(src + 4);
            union { ushort_t us[8]; uint4 v; } p;
            p.us[0] = f2bf(x.x); p.us[1] = f2bf(x.y);
            p.us[2] = f2bf(x.z); p.us[3] = f2bf(x.w);
            p.us[4] = f2bf(y.x); p.us[5] = f2bf(y.y);
            p.us[6] = f2bf(y.z); p.us[7] = f2bf(y.w);
            *(uint4*)&As[row * 64 + (su_ << 3)] = p.v;
        }
        // ---- stage B: u2 bf16, 16B copy with pre-swizzled source
#pragma unroll
        for (int w = 0; w < 2; ++w) {
            int row = srow + w * 64;
            int cb = (su_ ^ r7) << 4;  // byte offset in 128B row
            uint4 val = *(const uint4*)((const char*)u2 +
                        (((size_t)(b << 7) + row) * H + k0) * 2 + cb);
            *(uint4*)&Bs[row * 64 + (su_ << 3)] = val;
        }
        __syncthreads();
#pragma unroll
        for (int ks = 0; ks < 2; ++ks) {
            bf16x8 af[2], bfr[4];
            int cbyte = ks * 64 + ((lane >> 4) << 4);
#pragma unroll
            for (int mi = 0; mi < 2; ++mi) {
                int row = wr * 32 + mi * 16 + (lane & 15);
                af[mi] = *(const bf16x8*)&As[row * 64 + ((cbyte ^ ((row & 7) << 4)) >> 1)];
            }
#pragma unroll
            for (int nj = 0; nj < 4; ++nj) {
                int row = wc * 64 + nj * 16 + (lane & 15);
                bfr[nj] = *(const bf16x8*)&Bs[row * 64 + ((cbyte ^ ((row & 7) << 4)) >> 1)];
            }
#pragma unroll
            for (int mi = 0; mi < 2; ++mi)
#pragma unroll
                for (int nj = 0; nj < 4; ++nj)
                    acc[mi][nj] = __builtin_amdgcn_mfma_f32_16x16x32_bf16(
                        af[mi], bfr[nj], acc[mi][nj], 0, 0, 0);
        }
        __syncthreads();
    }

    // ---- epilogue: +suB, bf16 store, row-max, column (max,sumexp) partials
    const int jbase = wc * 64 + (lane & 15);
    float rowmax[2][4];
#pragma unroll
    for (int mi = 0; mi < 2; ++mi)
#pragma unroll
        for (int r = 0; r < 4; ++r) rowmax[mi][r] = -INFINITY;
    float cmv[4], csv[4];
#pragma unroll
    for (int nj = 0; nj < 4; ++nj) {
        float su_v = suB[(b << 7) + jbase + nj * 16];
        float tmp[8];
        float cm = -INFINITY;
#pragma unroll
        for (int mi = 0; mi < 2; ++mi)
#pragma unroll
            for (int r = 0; r < 4; ++r) {
                float sv = acc[mi][nj][r] + su_v;
                unsigned short sb = f2bf(sv);
                float svb = bf2f(sb);
                int t = t0 + wr * 32 + mi * 16 + ((lane >> 4) << 2) + r;
                Sb[((size_t)(b << 10) + t) * J + jbase + nj * 16] = sb;
                tmp[mi * 4 + r] = svb;
                cm = fmaxf(cm, svb);
                rowmax[mi][r] = fmaxf(rowmax[mi][r], svb);
            }
        float cs = 0.0f;
#pragma unroll
        for (int i = 0; i < 8; ++i) cs += __expf(tmp[i] - cm);
        cmv[nj] = cm;
        csv[nj] = cs;
    }
    // row-max across lanes sharing a row (vary lane&15)
#pragma unroll
    for (int mi = 0; mi < 2; ++mi)
#pragma unroll
        for (int r = 0; r < 4; ++r) {
            float v = rowmax[mi][r];
#pragma unroll
            for (int off = 1; off < 16; off <<= 1) v = fmaxf(v, __shfl_xor(v, off));
            if ((lane & 15) == 0) {
                int row = wr * 32 + mi * 16 + ((lane >> 4) << 2) + r;
                rm_red[wc][row] = v;
            }
        }
    // column stats across the 4 row-quads (vary lane>>4)
#pragma unroll
    for (int nj = 0; nj < 4; ++nj) {
        float cm = cmv[nj], cs = csv[nj];
#pragma unroll
        for (int off = 16; off < 64; off <<= 1) {
            float om = __shfl_xor(cm, off);
            float os = __shfl_xor(cs, off);
            float nm = fmaxf(cm, om);
            cs = cs * __expf(cm - nm) + os * __expf(om - nm);
            cm = nm;
        }
        if (lane < 16) {
            cm_red[wr][wc * 64 + nj * 16 + lane] = cm;
            cs_red[wr][wc * 64 + nj * 16 + lane] = cs;
        }
    }
    __syncthreads();
    if (tid < 128) {
        Mrow[(b << 10) + t0 + tid] = fmaxf(rm_red[0][tid], rm_red[1][tid]);
    } else if (tid < 256) {
        int j = tid - 128;
        float m = cm_red[0][j], s = cs_red[0][j];
#pragma unroll
        for (int r = 1; r < 4; ++r) {
            float m2 = cm_red[r][j], s2 = cs_red[r][j];
            float nm = fmaxf(m, m2);
            s = s * __expf(m - nm) + s2 * __expf(m2 - nm);
            m = nm;
        }
        int col = (b << 7) + j;
        pcm[col * 8 + blockIdx.x] = m;
        pcs[col * 8 + blockIdx.x] = s;
    }
}

// ---------------------------------------------------------------------------
// k_colstats_red: merge 8 t-block partials per column
// ---------------------------------------------------------------------------
__global__ __launch_bounds__(256) void k_colstats_red(const float* __restrict__ pmax,
                                                      const float* __restrict__ psum,
                                                      float* __restrict__ cmax,
                                                      float* __restrict__ cinv) {
    int col = blockIdx.x * 256 + threadIdx.x;
    float m = -INFINITY, s = 0.0f;
#pragma unroll
    for (int r = 0; r < 8; ++r) {
        float m2 = pmax[col * 8 + r], s2 = psum[col * 8 + r];
        float nm = fmaxf(m, m2);
        s = s * __expf(m - nm) + s2 * __expf(m2 - nm);
        m = nm;
    }
    cmax[col] = m;
    cinv[col] = 1.0f / s;
}

// ---------------------------------------------------------------------------
// k_btstats: per-batch softmax stats over Mrow
// ---------------------------------------------------------------------------
__global__ __launch_bounds__(256) void k_btstats(const float* __restrict__ Mrow,
                                                 float* __restrict__ btmax,
                                                 float* __restrict__ btinv) {
    int b = blockIdx.x;
    int tid = threadIdx.x;
    __shared__ float red[256];
    float m = -INFINITY;
    for (int t = tid; t < T; t += 256) m = fmaxf(m, Mrow[(b << 10) + t]);
    red[tid] = m;
    __syncthreads();
    for (int o = 128; o; o >>= 1) {
        if (tid < o) red[tid] = fmaxf(red[tid], red[tid + o]);
        __syncthreads();
    }
    m = red[0];
    __syncthreads();
    float s = 0.0f;
    for (int t = tid; t < T; t += 256) s += __expf(Mrow[(b << 10) + t] - m);
    red[tid] = s;
    __syncthreads();
    for (int o = 128; o; o >>= 1) {
        if (tid < o) red[tid] += red[tid + o];
        __syncthreads();
    }
    if (tid == 0) {
        btmax[b] = m;
        btinv[b] = 1.0f / red[0];
    }
}

// ---------------------------------------------------------------------------
// k_pnorm: in-place S_bf -> P_bf = bf16(exp(S - cmax[col]) * cinv[col])
// ---------------------------------------------------------------------------
__global__ __launch_bounds__(256) void k_pnorm(ushort_t* __restrict__ S,
                                               const float* __restrict__ cmax,
                                               const float* __restrict__ cinv) {
    size_t idx = (size_t)blockIdx.x * 256 + threadIdx.x;  // ushort8 granule
    size_t e = idx * 8;
    int b = (int)(e >> 17);
    int j = (int)(e & 127);
    uint4 v = ((uint4*)S)[idx];
    ushort_t* us = (ushort_t*)&v;
    const float* cm = &cmax[(b << 7) + j];
    const float* ci = &cinv[(b << 7) + j];
#pragma unroll
    for (int i = 0; i < 8; ++i) {
        float r = __expf(bf2f(us[i]) - cm[i]) * ci[i];
        us[i] = f2bf(r);
    }
    ((uint4*)S)[idx] = v;
}

// ---------------------------------------------------------------------------
// k_q2c_part / k_q2c_red: q2c[b,d] = sum_t bt[t]*h[b,t,d]
// ---------------------------------------------------------------------------
__global__ __launch_bounds__(256) void k_q2c_part(const float* __restrict__ h,
                                                  const float* __restrict__ Mrow,
                                                  const float* __restrict__ btmax,
                                                  const float* __restrict__ btinv,
                                                  float* __restrict__ part) {
    int b = blockIdx.z, tc = blockIdx.y;
    int d = blockIdx.x * 256 + threadIdx.x;
    __shared__ float wbt[64];
    int t0 = tc * 64;
    if (threadIdx.x < 64)
        wbt[threadIdx.x] = __expf(Mrow[(b << 10) + t0 + threadIdx.x] - btmax[b]) * btinv[b];
    __syncthreads();
    float acc = 0.0f;
#pragma unroll 4
    for (int i = 0; i < 64; ++i)
        acc += wbt[i] * h[((size_t)(b << 10) + t0 + i) * H + d];
    part[((size_t)(b * 16) + tc) * H + d] = acc;
}

__global__ __launch_bounds__(256) void k_q2c_red(const float* __restrict__ part,
                                                 float* __restrict__ q2c) {
    int b = blockIdx.y;
    int d = blockIdx.x * 256 + threadIdx.x;
    float acc = 0.0f;
#pragma unroll
    for (int tc = 0; tc < 16; ++tc)
        acc += part[((size_t)(b * 16) + tc) * H + d];
    q2c[(b << 10) + d] = acc;
}

// ---------------------------------------------------------------------------
// k_gemm2g: c2q = P @ u (MFMA, A=P[t][j], B=uT[d][j]), fused G writer
// 128x128 tile, K=J=128 in 2 steps, 256 thr = 4 waves (2x2), 64x64/wave
// ---------------------------------------------------------------------------
__global__ __launch_bounds__(256) void k_gemm2g(const ushort_t* __restrict__ P,
                                                const ushort_t* __restrict__ uT,
                                                const float* __restrict__ h,
                                                const float* __restrict__ q2c,
                                                float* __restrict__ G) {
    const int b = blockIdx.z;
    const int t0 = blockIdx.y * 128;
    const int d0 = blockIdx.x * 128;
    __shared__ ushort_t Ps[128 * 64];
    __shared__ ushort_t Us[128 * 64];
    const int tid = threadIdx.x;
    const int lane = tid & 63, wid = tid >> 6;
    const int wr = wid >> 1, wc = wid & 1;
    f32x4 acc[4][4] = {};

    for (int j0 = 0; j0 < J; j0 += 64) {
#pragma unroll
        for (int w = 0; w < 4; ++w) {
            int row = w * 32 + (tid >> 3);
            int u_ = tid & 7;
            int cb = (u_ ^ ((tid >> 3) & 7)) << 4;
            uint4 va = *(const uint4*)((const char*)P +
                       (((size_t)(b << 10) + t0 + row) * J + j0) * 2 + cb);
            *(uint4*)&Ps[row * 64 + (u_ << 3)] = va;
            uint4 vb = *(const uint4*)((const char*)uT +
                       (((size_t)(b << 10) + d0 + row) * J + j0) * 2 + cb);
            *(uint4*)&Us[row * 64 + (u_ << 3)] = vb;
        }
        __syncthreads();
#pragma unroll
        for (int ks = 0; ks < 2; ++ks) {
            bf16x8 af[4], bfr[4];
            int cbyte = ks * 64 + ((lane >> 4) << 4);
#pragma unroll
            for (int mi = 0; mi < 4; ++mi) {
                int row = wr * 64 + mi * 16 + (lane & 15);
                af[mi] = *(const bf16x8*)&Ps[row * 64 + ((cbyte ^ ((row & 7) << 4)) >> 1)];
            }
#pragma unroll
            for (int nj = 0; nj < 4; ++nj) {
                int row = wc * 64 + nj * 16 + (lane & 15);
                bfr[nj] = *(const bf16x8*)&Us[row * 64 + ((cbyte ^ ((row & 7) << 4)) >> 1)];
            }
#pragma unroll
            for (int mi = 0; mi < 4; ++mi)
#pragma unroll
                for (int nj = 0; nj < 4; ++nj)
                    acc[mi][nj] = __builtin_amdgcn_mfma_f32_16x16x32_bf16(
                        af[mi], bfr[nj], acc[mi][nj], 0, 0, 0);
        }
        __syncthreads();
    }

    // epilogue: G = [h, c2q, h*c2q, h*q2c]
    const int dbase = d0 + wc * 64 + (lane & 15);
    float qv[4];
#pragma unroll
    for (int nj = 0; nj < 4; ++nj) qv[nj] = q2c[(b << 10) + dbase + nj * 16];
#pragma unroll
    for (int mi = 0; mi < 4; ++mi) {
#pragma unroll
        for (int r = 0; r < 4; ++r) {
            int t = t0 + wr * 64 + mi * 16 + ((lane >> 4) << 2) + r;
            size_t hrow = ((size_t)(b << 10) + t) * H;
            size_t grow = ((size_t)(b << 10) + t) * (4 * H);
#pragma unroll
            for (int nj = 0; nj < 4; ++nj) {
                int d = dbase + nj * 16;
                float cv = acc[mi][nj][r];
                float hv = h[hrow + d];
                G[grow + d] = hv;
                G[grow + H + d] = cv;
                G[grow + 2 * H + d] = hv * cv;
                G[grow + 3 * H + d] = hv * qv[nj];
            }
        }
    }
}

extern "C" void kernel_launch(void* const* d_in, const int* in_sizes, int n_in,
                              void* d_out, int out_size, void* d_ws, size_t ws_size,
                              hipStream_t stream) {
    const float* h = (const float*)d_in[0];
    const float* u = (const float*)d_in[1];
    const float* w = (const float*)d_in[2];
    const float* bb = (const float*)d_in[3];
    float* G = (float*)d_out;

    char* p = (char*)d_ws;
    ushort_t* Sb = (ushort_t*)p; p += (size_t)B * T * J * 2;   // 8.4 MB
    ushort_t* u2 = (ushort_t*)p; p += (size_t)B * J * H * 2;   // 8.4 MB
    ushort_t* uT = (ushort_t*)p; p += (size_t)B * H * J * 2;   // 8.4 MB
    float* suB = (float*)p; p += B * J * 4;
    float* pcm = (float*)p; p += B * J * 8 * 4;
    float* pcs = (float*)p; p += B * J * 8 * 4;
    float* cmax = (float*)p; p += B * J * 4;
    float* cinv = (float*)p; p += B * J * 4;
    float* Mrow = (float*)p; p += B * T * 4;
    float* btmax = (float*)p; p += B * 4;
    float* btinv = (float*)p; p += B * 4;
    float* q2c = (float*)p; p += B * H * 4;
    float* qpart = (float*)p;  // B*16*H*4 = 2.1 MB

    k_su<<<dim3(B * J / 4), 256, 0, stream>>>(u, w, bb, suB);
    k_uprep<<<dim3(H / 64, J / 64, B), 256, 0, stream>>>(u, w, u2, uT);
    k_gemm1<<<dim3(T / 128, B), 512, 0, stream>>>(h, u2, suB, Sb, Mrow, pcm, pcs);
    k_colstats_red<<<dim3(B * J / 256), 256, 0, stream>>>(pcm, pcs, cmax, cinv);
    k_btstats<<<dim3(B), 256, 0, stream>>>(Mrow, btmax, btinv);
    k_pnorm<<<dim3(B * T * J / (8 * 256)), 256, 0, stream>>>(Sb, cmax, cinv);
    k_q2c_part<<<dim3(H / 256, 16, B), 256, 0, stream>>>(h, Mrow, btmax, btinv, qpart);
    k_q2c_red<<<dim3(H / 256, B), 256, 0, stream>>>(qpart, q2c);
    k_gemm2g<<<dim3(H / 128, T / 128, B), 256, 0, stream>>>(Sb, uT, h, q2c, G);
}

// Round 3
// 298.174 us; speedup vs baseline: 1.2153x; 1.0244x over previous
//
#include <hip/hip_runtime.h>
#include <cstddef>
#include <cstdint>

#define B 32
#define T 1024
#define J 128
#define H 1024

typedef unsigned short ushort_t;
typedef __attribute__((ext_vector_type(8))) short bf16x8;
typedef __attribute__((ext_vector_type(4))) float f32x4;

__device__ __forceinline__ unsigned short f2bf(float f) {
    union { float f; unsigned u; } v;
    v.f = f;
    return (unsigned short)((v.u + 0x7FFFu + ((v.u >> 16) & 1u)) >> 16);
}
__device__ __forceinline__ float bf2f(unsigned short s) {
    union { unsigned u; float f; } v;
    v.u = ((unsigned)s) << 16;
    return v.f;
}

// ---------------------------------------------------------------------------
// k_uprep: u2_bf[b,j,d] = bf16(wh[d] + wm[d]*u), uT_bf[b,d,j] = bf16(u),
// fused partial dot pdot[b*J+j][16] = sum_{d in 64-tile} u*wu
// grid (H/64=16, J/64=2, B), 256 thr
// ---------------------------------------------------------------------------
__global__ __launch_bounds__(256) void k_uprep(const float* __restrict__ u,
                                               const float* __restrict__ w,
                                               ushort_t* __restrict__ u2,
                                               ushort_t* __restrict__ uT,
                                               float* __restrict__ pdot) {
    int b = blockIdx.z, j0 = blockIdx.y * 64, d0 = blockIdx.x * 64;
    __shared__ ushort_t tile[64][72];
    int tid = threadIdx.x;
    int jr = tid >> 2, c0 = (tid & 3) * 16;
    const float* wh = w;
    const float* wu = w + H;
    const float* wm = w + 2 * H;
    size_t src = ((size_t)(b << 7) + j0 + jr) * H + d0 + c0;
    union { ushort_t us[16]; uint4 v[2]; } o;
    float dot = 0.0f;
#pragma unroll
    for (int i = 0; i < 16; i += 4) {
        float4 x = *(const float4*)&u[src + i];
        const float* xp = &x.x;
#pragma unroll
        for (int k = 0; k < 4; ++k) {
            int d = d0 + c0 + i + k;
            float uu = xp[k];
            o.us[i + k] = f2bf(wh[d] + wm[d] * uu);
            tile[jr][c0 + i + k] = f2bf(uu);
            dot += uu * wu[d];
        }
    }
    *(uint4*)&u2[src] = o.v[0];
    *(uint4*)&u2[src + 8] = o.v[1];
    // reduce dot across the 4 threads of this row (consecutive lanes)
    dot += __shfl_xor(dot, 1);
    dot += __shfl_xor(dot, 2);
    if ((tid & 3) == 0)
        pdot[((size_t)(b << 7) + j0 + jr) * 16 + blockIdx.x] = dot;
    __syncthreads();
    int dr = tid >> 2, jc0 = (tid & 3) * 16;
    union { ushort_t us[16]; uint4 v[2]; } t2;
#pragma unroll
    for (int i = 0; i < 16; ++i) t2.us[i] = tile[jc0 + i][dr];
    size_t dst = ((size_t)(b << 10) + d0 + dr) * J + j0 + jc0;
    *(uint4*)&uT[dst] = t2.v[0];
    *(uint4*)&uT[dst + 8] = t2.v[1];
}

// ---------------------------------------------------------------------------
// k_sured: suB[col] = sum_16 pdot[col][r] + b0
// ---------------------------------------------------------------------------
__global__ __launch_bounds__(256) void k_sured(const float* __restrict__ pdot,
                                               const float* __restrict__ bscal,
                                               float* __restrict__ suB) {
    int col = blockIdx.x * 256 + threadIdx.x;
    float s = 0.0f;
#pragma unroll
    for (int r = 0; r < 16; ++r) s += pdot[(size_t)col * 16 + r];
    suB[col] = s + bscal[0];
}

// ---------------------------------------------------------------------------
// k_gemm1: S_bf = bf16(h @ u2^T + suB), fused Mrow + column partials.
// XCD-swizzled grid: 256 blocks, 512 thr, 128x128 tile, BK=64.
// ---------------------------------------------------------------------------
__global__ __launch_bounds__(512) void k_gemm1(const float* __restrict__ h,
                                               const ushort_t* __restrict__ u2,
                                               const float* __restrict__ suB,
                                               ushort_t* __restrict__ Sb,
                                               float* __restrict__ Mrow,
                                               float* __restrict__ pcm,
                                               float* __restrict__ pcs) {
    const int lid = blockIdx.x;
    const int b = (lid & 7) * 4 + (lid >> 6);  // 4 batches per XCD
    const int tt = (lid >> 3) & 7;
    const int t0 = tt * 128;
    __shared__ ushort_t As[128 * 64];
    __shared__ ushort_t Bs[128 * 64];
    __shared__ float rm_red[2][128];
    __shared__ float cm_red[4][128];
    __shared__ float cs_red[4][128];
    const int tid = threadIdx.x;
    const int lane = tid & 63, wid = tid >> 6;
    const int wr = wid >> 1, wc = wid & 1;

    f32x4 acc[2][4] = {};

    const int srow = wid * 8 + (lane >> 3);
    const int su_ = lane & 7;
    const int r7 = lane >> 3;

    for (int k0 = 0; k0 < H; k0 += 64) {
#pragma unroll
        for (int w = 0; w < 2; ++w) {
            int row = srow + w * 64;
            int kk = (su_ ^ r7) << 3;
            const float* src = h + ((size_t)(b << 10) + t0 + row) * H + k0 + kk;
            float4 x = *(const float4*)src;
            float4 y = *(const float4*)(src + 4);
            union { ushort_t us[8]; uint4 v; } p;
            p.us[0] = f2bf(x.x); p.us[1] = f2bf(x.y);
            p.us[2] = f2bf(x.z); p.us[3] = f2bf(x.w);
            p.us[4] = f2bf(y.x); p.us[5] = f2bf(y.y);
            p.us[6] = f2bf(y.z); p.us[7] = f2bf(y.w);
            *(uint4*)&As[row * 64 + (su_ << 3)] = p.v;
        }
#pragma unroll
        for (int w = 0; w < 2; ++w) {
            int row = srow + w * 64;
            int cb = (su_ ^ r7) << 4;
            uint4 val = *(const uint4*)((const char*)u2 +
                        (((size_t)(b << 7) + row) * H + k0) * 2 + cb);
            *(uint4*)&Bs[row * 64 + (su_ << 3)] = val;
        }
        __syncthreads();
#pragma unroll
        for (int ks = 0; ks < 2; ++ks) {
            bf16x8 af[2], bfr[4];
            int cbyte = ks * 64 + ((lane >> 4) << 4);
#pragma unroll
            for (int mi = 0; mi < 2; ++mi) {
                int row = wr * 32 + mi * 16 + (lane & 15);
                af[mi] = *(const bf16x8*)&As[row * 64 + ((cbyte ^ ((row & 7) << 4)) >> 1)];
            }
#pragma unroll
            for (int nj = 0; nj < 4; ++nj) {
                int row = wc * 64 + nj * 16 + (lane & 15);
                bfr[nj] = *(const bf16x8*)&Bs[row * 64 + ((cbyte ^ ((row & 7) << 4)) >> 1)];
            }
#pragma unroll
            for (int mi = 0; mi < 2; ++mi)
#pragma unroll
                for (int nj = 0; nj < 4; ++nj)
                    acc[mi][nj] = __builtin_amdgcn_mfma_f32_16x16x32_bf16(
                        af[mi], bfr[nj], acc[mi][nj], 0, 0, 0);
        }
        __syncthreads();
    }

    const int jbase = wc * 64 + (lane & 15);
    float rowmax[2][4];
#pragma unroll
    for (int mi = 0; mi < 2; ++mi)
#pragma unroll
        for (int r = 0; r < 4; ++r) rowmax[mi][r] = -INFINITY;
    float cmv[4], csv[4];
#pragma unroll
    for (int nj = 0; nj < 4; ++nj) {
        float su_v = suB[(b << 7) + jbase + nj * 16];
        float tmp[8];
        float cm = -INFINITY;
#pragma unroll
        for (int mi = 0; mi < 2; ++mi)
#pragma unroll
            for (int r = 0; r < 4; ++r) {
                float sv = acc[mi][nj][r] + su_v;
                unsigned short sb = f2bf(sv);
                float svb = bf2f(sb);
                int t = t0 + wr * 32 + mi * 16 + ((lane >> 4) << 2) + r;
                Sb[((size_t)(b << 10) + t) * J + jbase + nj * 16] = sb;
                tmp[mi * 4 + r] = svb;
                cm = fmaxf(cm, svb);
                rowmax[mi][r] = fmaxf(rowmax[mi][r], svb);
            }
        float cs = 0.0f;
#pragma unroll
        for (int i = 0; i < 8; ++i) cs += __expf(tmp[i] - cm);
        cmv[nj] = cm;
        csv[nj] = cs;
    }
#pragma unroll
    for (int mi = 0; mi < 2; ++mi)
#pragma unroll
        for (int r = 0; r < 4; ++r) {
            float v = rowmax[mi][r];
#pragma unroll
            for (int off = 1; off < 16; off <<= 1) v = fmaxf(v, __shfl_xor(v, off));
            if ((lane & 15) == 0) {
                int row = wr * 32 + mi * 16 + ((lane >> 4) << 2) + r;
                rm_red[wc][row] = v;
            }
        }
#pragma unroll
    for (int nj = 0; nj < 4; ++nj) {
        float cm = cmv[nj], cs = csv[nj];
#pragma unroll
        for (int off = 16; off < 64; off <<= 1) {
            float om = __shfl_xor(cm, off);
            float os = __shfl_xor(cs, off);
            float nm = fmaxf(cm, om);
            cs = cs * __expf(cm - nm) + os * __expf(om - nm);
            cm = nm;
        }
        if (lane < 16) {
            cm_red[wr][wc * 64 + nj * 16 + lane] = cm;
            cs_red[wr][wc * 64 + nj * 16 + lane] = cs;
        }
    }
    __syncthreads();
    if (tid < 128) {
        Mrow[(b << 10) + t0 + tid] = fmaxf(rm_red[0][tid], rm_red[1][tid]);
    } else if (tid < 256) {
        int j = tid - 128;
        float m = cm_red[0][j], s = cs_red[0][j];
#pragma unroll
        for (int r = 1; r < 4; ++r) {
            float m2 = cm_red[r][j], s2 = cs_red[r][j];
            float nm = fmaxf(m, m2);
            s = s * __expf(m - nm) + s2 * __expf(m2 - nm);
            m = nm;
        }
        int col = (b << 7) + j;
        pcm[col * 8 + tt] = m;
        pcs[col * 8 + tt] = s;
    }
}

// ---------------------------------------------------------------------------
// k_stats: blocks 0..15 -> column softmax stats; blocks 16..47 -> bt stats
// ---------------------------------------------------------------------------
__global__ __launch_bounds__(256) void k_stats(const float* __restrict__ pmax,
                                               const float* __restrict__ psum,
                                               const float* __restrict__ Mrow,
                                               float* __restrict__ cmax,
                                               float* __restrict__ cinv,
                                               float* __restrict__ btmax,
                                               float* __restrict__ btinv) {
    __shared__ float red[256];
    int tid = threadIdx.x;
    if (blockIdx.x < 16) {
        int col = blockIdx.x * 256 + tid;
        float m = -INFINITY, s = 0.0f;
#pragma unroll
        for (int r = 0; r < 8; ++r) {
            float m2 = pmax[col * 8 + r], s2 = psum[col * 8 + r];
            float nm = fmaxf(m, m2);
            s = s * __expf(m - nm) + s2 * __expf(m2 - nm);
            m = nm;
        }
        cmax[col] = m;
        cinv[col] = 1.0f / s;
    } else {
        int b = blockIdx.x - 16;
        float m = -INFINITY;
        for (int t = tid; t < T; t += 256) m = fmaxf(m, Mrow[(b << 10) + t]);
        red[tid] = m;
        __syncthreads();
        for (int o = 128; o; o >>= 1) {
            if (tid < o) red[tid] = fmaxf(red[tid], red[tid + o]);
            __syncthreads();
        }
        m = red[0];
        __syncthreads();
        float s = 0.0f;
        for (int t = tid; t < T; t += 256) s += __expf(Mrow[(b << 10) + t] - m);
        red[tid] = s;
        __syncthreads();
        for (int o = 128; o; o >>= 1) {
            if (tid < o) red[tid] += red[tid + o];
            __syncthreads();
        }
        if (tid == 0) {
            btmax[b] = m;
            btinv[b] = 1.0f / red[0];
        }
    }
}

// ---------------------------------------------------------------------------
// k_pnorm: in-place S_bf -> P_bf
// ---------------------------------------------------------------------------
__global__ __launch_bounds__(256) void k_pnorm(ushort_t* __restrict__ S,
                                               const float* __restrict__ cmax,
                                               const float* __restrict__ cinv) {
    size_t idx = (size_t)blockIdx.x * 256 + threadIdx.x;
    size_t e = idx * 8;
    int b = (int)(e >> 17);
    int j = (int)(e & 127);
    uint4 v = ((uint4*)S)[idx];
    ushort_t* us = (ushort_t*)&v;
    const float* cm = &cmax[(b << 7) + j];
    const float* ci = &cinv[(b << 7) + j];
#pragma unroll
    for (int i = 0; i < 8; ++i) {
        float r = __expf(bf2f(us[i]) - cm[i]) * ci[i];
        us[i] = f2bf(r);
    }
    ((uint4*)S)[idx] = v;
}

// ---------------------------------------------------------------------------
// k_q2c_part (float4) / k_q2c_red
// ---------------------------------------------------------------------------
__global__ __launch_bounds__(256) void k_q2c_part(const float* __restrict__ h,
                                                  const float* __restrict__ Mrow,
                                                  const float* __restrict__ btmax,
                                                  const float* __restrict__ btinv,
                                                  float* __restrict__ part) {
    int tc = blockIdx.x, b = blockIdx.y;
    int d4 = threadIdx.x * 4;
    __shared__ float wbt[64];
    int t0 = tc * 64;
    if (threadIdx.x < 64)
        wbt[threadIdx.x] = __expf(Mrow[(b << 10) + t0 + threadIdx.x] - btmax[b]) * btinv[b];
    __syncthreads();
    float4 acc = make_float4(0.f, 0.f, 0.f, 0.f);
#pragma unroll 4
    for (int i = 0; i < 64; ++i) {
        float4 x = *(const float4*)&h[((size_t)(b << 10) + t0 + i) * H + d4];
        float wv = wbt[i];
        acc.x += wv * x.x; acc.y += wv * x.y;
        acc.z += wv * x.z; acc.w += wv * x.w;
    }
    *(float4*)&part[(((size_t)b * 16 + tc) << 10) + d4] = acc;
}

__global__ __launch_bounds__(256) void k_q2c_red(const float* __restrict__ part,
                                                 float* __restrict__ q2c) {
    int b = blockIdx.y;
    int d4 = threadIdx.x * 4;
    float4 acc = make_float4(0.f, 0.f, 0.f, 0.f);
#pragma unroll
    for (int tc = 0; tc < 16; ++tc) {
        float4 x = *(const float4*)&part[(((size_t)b * 16 + tc) << 10) + d4];
        acc.x += x.x; acc.y += x.y; acc.z += x.z; acc.w += x.w;
    }
    *(float4*)&q2c[(b << 10) + d4] = acc;
}

// ---------------------------------------------------------------------------
// k_gemm2g: c2q = P @ u via MFMA with A=uT (d rows), B=P (t cols) so that
// C rows = d -> each lane holds 4 consecutive d -> float4 G stores.
// XCD-swizzled: batch pinned to one XCD for P/uT L2 reuse.
// ---------------------------------------------------------------------------
__global__ __launch_bounds__(256) void k_gemm2g(const ushort_t* __restrict__ P,
                                                const ushort_t* __restrict__ uT,
                                                const float* __restrict__ h,
                                                const float* __restrict__ q2c,
                                                float* __restrict__ G) {
    const int lid = blockIdx.x;
    const int seq = lid >> 3;
    const int b = (lid & 7) * 4 + (seq >> 6);
    const int inner = seq & 63;
    const int d0 = (inner >> 3) * 128;
    const int t0 = (inner & 7) * 128;
    __shared__ ushort_t Ps[128 * 64];
    __shared__ ushort_t Us[128 * 64];
    const int tid = threadIdx.x;
    const int lane = tid & 63, wid = tid >> 6;
    const int wd = wid >> 1, wt = wid & 1;
    f32x4 acc[4][4] = {};

    for (int j0 = 0; j0 < J; j0 += 64) {
#pragma unroll
        for (int w = 0; w < 4; ++w) {
            int row = w * 32 + (tid >> 3);
            int u_ = tid & 7;
            int cb = (u_ ^ ((tid >> 3) & 7)) << 4;
            uint4 va = *(const uint4*)((const char*)P +
                       (((size_t)(b << 10) + t0 + row) * J + j0) * 2 + cb);
            *(uint4*)&Ps[row * 64 + (u_ << 3)] = va;
            uint4 vb = *(const uint4*)((const char*)uT +
                       (((size_t)(b << 10) + d0 + row) * J + j0) * 2 + cb);
            *(uint4*)&Us[row * 64 + (u_ << 3)] = vb;
        }
        __syncthreads();
#pragma unroll
        for (int ks = 0; ks < 2; ++ks) {
            bf16x8 af[4], bfr[4];
            int cbyte = ks * 64 + ((lane >> 4) << 4);
#pragma unroll
            for (int mi = 0; mi < 4; ++mi) {
                int row = wd * 64 + mi * 16 + (lane & 15);
                af[mi] = *(const bf16x8*)&Us[row * 64 + ((cbyte ^ ((row & 7) << 4)) >> 1)];
            }
#pragma unroll
            for (int nj = 0; nj < 4; ++nj) {
                int row = wt * 64 + nj * 16 + (lane & 15);
                bfr[nj] = *(const bf16x8*)&Ps[row * 64 + ((cbyte ^ ((row & 7) << 4)) >> 1)];
            }
#pragma unroll
            for (int mi = 0; mi < 4; ++mi)
#pragma unroll
                for (int nj = 0; nj < 4; ++nj)
                    acc[mi][nj] = __builtin_amdgcn_mfma_f32_16x16x32_bf16(
                        af[mi], bfr[nj], acc[mi][nj], 0, 0, 0);
        }
        __syncthreads();
    }

    // epilogue: lane owns d = drow..drow+3 (consecutive), t = tcol
    const int lane15 = lane & 15, lq = lane >> 4;
#pragma unroll
    for (int mi = 0; mi < 4; ++mi) {
        int drow = d0 + wd * 64 + mi * 16 + lq * 4;
        float4 qv = *(const float4*)&q2c[(b << 10) + drow];
#pragma unroll
        for (int nj = 0; nj < 4; ++nj) {
            int tcol = t0 + wt * 64 + nj * 16 + lane15;
            size_t rowoff = ((size_t)(b << 10) + tcol);
            float4 hv = *(const float4*)&h[rowoff * H + drow];
            f32x4 a = acc[mi][nj];
            float4 cv = make_float4(a[0], a[1], a[2], a[3]);
            size_t gp = rowoff * (4 * H) + drow;
            *(float4*)&G[gp] = hv;
            *(float4*)&G[gp + H] = cv;
            *(float4*)&G[gp + 2 * H] = make_float4(hv.x * cv.x, hv.y * cv.y,
                                                   hv.z * cv.z, hv.w * cv.w);
            *(float4*)&G[gp + 3 * H] = make_float4(hv.x * qv.x, hv.y * qv.y,
                                                   hv.z * qv.z, hv.w * qv.w);
        }
    }
}

extern "C" void kernel_launch(void* const* d_in, const int* in_sizes, int n_in,
                              void* d_out, int out_size, void* d_ws, size_t ws_size,
                              hipStream_t stream) {
    const float* h = (const float*)d_in[0];
    const float* u = (const float*)d_in[1];
    const float* w = (const float*)d_in[2];
    const float* bb = (const float*)d_in[3];
    float* G = (float*)d_out;

    char* p = (char*)d_ws;
    ushort_t* Sb = (ushort_t*)p; p += (size_t)B * T * J * 2;
    ushort_t* u2 = (ushort_t*)p; p += (size_t)B * J * H * 2;
    ushort_t* uT = (ushort_t*)p; p += (size_t)B * H * J * 2;
    float* pdot = (float*)p; p += (size_t)B * J * 16 * 4;
    float* suB = (float*)p; p += B * J * 4;
    float* pcm = (float*)p; p += B * J * 8 * 4;
    float* pcs = (float*)p; p += B * J * 8 * 4;
    float* cmax = (float*)p; p += B * J * 4;
    float* cinv = (float*)p; p += B * J * 4;
    float* Mrow = (float*)p; p += B * T * 4;
    float* btmax = (float*)p; p += B * 4;
    float* btinv = (float*)p; p += B * 4;
    float* q2c = (float*)p; p += B * H * 4;
    float* qpart = (float*)p;

    k_uprep<<<dim3(H / 64, J / 64, B), 256, 0, stream>>>(u, w, u2, uT, pdot);
    k_sured<<<dim3(B * J / 256), 256, 0, stream>>>(pdot, bb, suB);
    k_gemm1<<<dim3(256), 512, 0, stream>>>(h, u2, suB, Sb, Mrow, pcm, pcs);
    k_stats<<<dim3(48), 256, 0, stream>>>(pcm, pcs, Mrow, cmax, cinv, btmax, btinv);
    k_pnorm<<<dim3(B * T * J / (8 * 256)), 256, 0, stream>>>(Sb, cmax, cinv);
    k_q2c_part<<<dim3(16, B), 256, 0, stream>>>(h, Mrow, btmax, btinv, qpart);
    k_q2c_red<<<dim3(1, B), 256, 0, stream>>>(qpart, q2c);
    k_gemm2g<<<dim3(2048), 256, 0, stream>>>(Sb, uT, h, q2c, G);
}

// Round 4
// 294.122 us; speedup vs baseline: 1.2320x; 1.0138x over previous
//
#include <hip/hip_runtime.h>
#include <cstddef>
#include <cstdint>

#define B 32
#define T 1024
#define J 128
#define H 1024

typedef unsigned short ushort_t;
typedef __attribute__((ext_vector_type(8))) short bf16x8;
typedef __attribute__((ext_vector_type(4))) float f32x4;

__device__ __forceinline__ unsigned short f2bf(float f) {
    union { float f; unsigned u; } v;
    v.f = f;
    return (unsigned short)((v.u + 0x7FFFu + ((v.u >> 16) & 1u)) >> 16);
}
__device__ __forceinline__ float bf2f(unsigned short s) {
    union { unsigned u; float f; } v;
    v.u = ((unsigned)s) << 16;
    return v.f;
}

// ---------------------------------------------------------------------------
// k_uprep: u2_bf[b,j,d] = bf16(wh[d] + wm[d]*u), uT_bf[b,d,j] = bf16(u),
// fused partial dot pdot[(b*J+j)*16 + dtile] = sum u*wu
// ---------------------------------------------------------------------------
__global__ __launch_bounds__(256) void k_uprep(const float* __restrict__ u,
                                               const float* __restrict__ w,
                                               ushort_t* __restrict__ u2,
                                               ushort_t* __restrict__ uT,
                                               float* __restrict__ pdot) {
    int b = blockIdx.z, j0 = blockIdx.y * 64, d0 = blockIdx.x * 64;
    __shared__ ushort_t tile[64][72];
    int tid = threadIdx.x;
    int jr = tid >> 2, c0 = (tid & 3) * 16;
    const float* wh = w;
    const float* wu = w + H;
    const float* wm = w + 2 * H;
    size_t src = ((size_t)(b << 7) + j0 + jr) * H + d0 + c0;
    union { ushort_t us[16]; uint4 v[2]; } o;
    float dot = 0.0f;
#pragma unroll
    for (int i = 0; i < 16; i += 4) {
        float4 x = *(const float4*)&u[src + i];
        const float* xp = &x.x;
#pragma unroll
        for (int k = 0; k < 4; ++k) {
            int d = d0 + c0 + i + k;
            float uu = xp[k];
            o.us[i + k] = f2bf(wh[d] + wm[d] * uu);
            tile[jr][c0 + i + k] = f2bf(uu);
            dot += uu * wu[d];
        }
    }
    *(uint4*)&u2[src] = o.v[0];
    *(uint4*)&u2[src + 8] = o.v[1];
    dot += __shfl_xor(dot, 1);
    dot += __shfl_xor(dot, 2);
    if ((tid & 3) == 0)
        pdot[((size_t)(b << 7) + j0 + jr) * 16 + blockIdx.x] = dot;
    __syncthreads();
    int dr = tid >> 2, jc0 = (tid & 3) * 16;
    union { ushort_t us[16]; uint4 v[2]; } t2;
#pragma unroll
    for (int i = 0; i < 16; ++i) t2.us[i] = tile[jc0 + i][dr];
    size_t dst = ((size_t)(b << 10) + d0 + dr) * J + j0 + jc0;
    *(uint4*)&uT[dst] = t2.v[0];
    *(uint4*)&uT[dst + 8] = t2.v[1];
}

// ---------------------------------------------------------------------------
// k_sured: suB[col] = sum_16 pdot[col][r] + b0
// ---------------------------------------------------------------------------
__global__ __launch_bounds__(256) void k_sured(const float* __restrict__ pdot,
                                               const float* __restrict__ bscal,
                                               float* __restrict__ suB) {
    int col = blockIdx.x * 256 + threadIdx.x;
    float s = 0.0f;
#pragma unroll
    for (int r = 0; r < 16; ++r) s += pdot[(size_t)col * 16 + r];
    suB[col] = s + bscal[0];
}

// ---------------------------------------------------------------------------
// k_gemm1: S_bf = bf16(h @ u2^T + suB); side-writes hbf = bf16(h).
// Fused Mrow + per-t-block column (max,sumexp) partials.
// XCD-swizzled: 256 blocks, 512 thr, 128x128 tile, BK=64.
// ---------------------------------------------------------------------------
__global__ __launch_bounds__(512) void k_gemm1(const float* __restrict__ h,
                                               const ushort_t* __restrict__ u2,
                                               const float* __restrict__ suB,
                                               ushort_t* __restrict__ Sb,
                                               ushort_t* __restrict__ hbf,
                                               float* __restrict__ Mrow,
                                               float* __restrict__ pcm,
                                               float* __restrict__ pcs) {
    const int lid = blockIdx.x;
    const int b = (lid & 7) * 4 + (lid >> 6);
    const int tt = (lid >> 3) & 7;
    const int t0 = tt * 128;
    __shared__ ushort_t As[128 * 64];
    __shared__ ushort_t Bs[128 * 64];
    __shared__ float rm_red[2][128];
    __shared__ float cm_red[4][128];
    __shared__ float cs_red[4][128];
    const int tid = threadIdx.x;
    const int lane = tid & 63, wid = tid >> 6;
    const int wr = wid >> 1, wc = wid & 1;

    f32x4 acc[2][4] = {};

    const int srow = wid * 8 + (lane >> 3);
    const int su_ = lane & 7;
    const int r7 = lane >> 3;

    for (int k0 = 0; k0 < H; k0 += 64) {
#pragma unroll
        for (int w = 0; w < 2; ++w) {
            int row = srow + w * 64;
            int kk = (su_ ^ r7) << 3;
            size_t hoff = ((size_t)(b << 10) + t0 + row) * H + k0 + kk;
            const float* src = h + hoff;
            float4 x = *(const float4*)src;
            float4 y = *(const float4*)(src + 4);
            union { ushort_t us[8]; uint4 v; } p;
            p.us[0] = f2bf(x.x); p.us[1] = f2bf(x.y);
            p.us[2] = f2bf(x.z); p.us[3] = f2bf(x.w);
            p.us[4] = f2bf(y.x); p.us[5] = f2bf(y.y);
            p.us[6] = f2bf(y.z); p.us[7] = f2bf(y.w);
            *(uint4*)&As[row * 64 + (su_ << 3)] = p.v;
            *(uint4*)&hbf[hoff] = p.v;  // side-product: bf16 h
        }
#pragma unroll
        for (int w = 0; w < 2; ++w) {
            int row = srow + w * 64;
            int cb = (su_ ^ r7) << 4;
            uint4 val = *(const uint4*)((const char*)u2 +
                        (((size_t)(b << 7) + row) * H + k0) * 2 + cb);
            *(uint4*)&Bs[row * 64 + (su_ << 3)] = val;
        }
        __syncthreads();
#pragma unroll
        for (int ks = 0; ks < 2; ++ks) {
            bf16x8 af[2], bfr[4];
            int cbyte = ks * 64 + ((lane >> 4) << 4);
#pragma unroll
            for (int mi = 0; mi < 2; ++mi) {
                int row = wr * 32 + mi * 16 + (lane & 15);
                af[mi] = *(const bf16x8*)&As[row * 64 + ((cbyte ^ ((row & 7) << 4)) >> 1)];
            }
#pragma unroll
            for (int nj = 0; nj < 4; ++nj) {
                int row = wc * 64 + nj * 16 + (lane & 15);
                bfr[nj] = *(const bf16x8*)&Bs[row * 64 + ((cbyte ^ ((row & 7) << 4)) >> 1)];
            }
#pragma unroll
            for (int mi = 0; mi < 2; ++mi)
#pragma unroll
                for (int nj = 0; nj < 4; ++nj)
                    acc[mi][nj] = __builtin_amdgcn_mfma_f32_16x16x32_bf16(
                        af[mi], bfr[nj], acc[mi][nj], 0, 0, 0);
        }
        __syncthreads();
    }

    const int jbase = wc * 64 + (lane & 15);
    float rowmax[2][4];
#pragma unroll
    for (int mi = 0; mi < 2; ++mi)
#pragma unroll
        for (int r = 0; r < 4; ++r) rowmax[mi][r] = -INFINITY;
    float cmv[4], csv[4];
#pragma unroll
    for (int nj = 0; nj < 4; ++nj) {
        float su_v = suB[(b << 7) + jbase + nj * 16];
        float tmp[8];
        float cm = -INFINITY;
#pragma unroll
        for (int mi = 0; mi < 2; ++mi)
#pragma unroll
            for (int r = 0; r < 4; ++r) {
                float sv = acc[mi][nj][r] + su_v;
                unsigned short sb = f2bf(sv);
                float svb = bf2f(sb);
                int t = t0 + wr * 32 + mi * 16 + ((lane >> 4) << 2) + r;
                Sb[((size_t)(b << 10) + t) * J + jbase + nj * 16] = sb;
                tmp[mi * 4 + r] = svb;
                cm = fmaxf(cm, svb);
                rowmax[mi][r] = fmaxf(rowmax[mi][r], svb);
            }
        float cs = 0.0f;
#pragma unroll
        for (int i = 0; i < 8; ++i) cs += __expf(tmp[i] - cm);
        cmv[nj] = cm;
        csv[nj] = cs;
    }
#pragma unroll
    for (int mi = 0; mi < 2; ++mi)
#pragma unroll
        for (int r = 0; r < 4; ++r) {
            float v = rowmax[mi][r];
#pragma unroll
            for (int off = 1; off < 16; off <<= 1) v = fmaxf(v, __shfl_xor(v, off));
            if ((lane & 15) == 0) {
                int row = wr * 32 + mi * 16 + ((lane >> 4) << 2) + r;
                rm_red[wc][row] = v;
            }
        }
#pragma unroll
    for (int nj = 0; nj < 4; ++nj) {
        float cm = cmv[nj], cs = csv[nj];
#pragma unroll
        for (int off = 16; off < 64; off <<= 1) {
            float om = __shfl_xor(cm, off);
            float os = __shfl_xor(cs, off);
            float nm = fmaxf(cm, om);
            cs = cs * __expf(cm - nm) + os * __expf(om - nm);
            cm = nm;
        }
        if (lane < 16) {
            cm_red[wr][wc * 64 + nj * 16 + lane] = cm;
            cs_red[wr][wc * 64 + nj * 16 + lane] = cs;
        }
    }
    __syncthreads();
    if (tid < 128) {
        Mrow[(b << 10) + t0 + tid] = fmaxf(rm_red[0][tid], rm_red[1][tid]);
    } else if (tid < 256) {
        int j = tid - 128;
        float m = cm_red[0][j], s = cs_red[0][j];
#pragma unroll
        for (int r = 1; r < 4; ++r) {
            float m2 = cm_red[r][j], s2 = cs_red[r][j];
            float nm = fmaxf(m, m2);
            s = s * __expf(m - nm) + s2 * __expf(m2 - nm);
            m = nm;
        }
        int col = (b << 7) + j;
        pcm[col * 8 + tt] = m;
        pcs[col * 8 + tt] = s;
    }
}

// ---------------------------------------------------------------------------
// k_q2c_part: self-contained bt softmax stats from Mrow, then partial
// q2c over a 64-row t-chunk reading hbf. grid (16, B), 256 thr.
// ---------------------------------------------------------------------------
__global__ __launch_bounds__(256) void k_q2c_part(const ushort_t* __restrict__ hbf,
                                                  const float* __restrict__ Mrow,
                                                  float* __restrict__ part) {
    int tc = blockIdx.x, b = blockIdx.y;
    int tid = threadIdx.x;
    __shared__ float red[256];
    __shared__ float wbt[64];
    const float* mr = Mrow + (b << 10);
    float m = fmaxf(fmaxf(mr[tid], mr[tid + 256]), fmaxf(mr[tid + 512], mr[tid + 768]));
    red[tid] = m;
    __syncthreads();
    for (int o = 128; o; o >>= 1) {
        if (tid < o) red[tid] = fmaxf(red[tid], red[tid + o]);
        __syncthreads();
    }
    m = red[0];
    __syncthreads();
    float s = 0.0f;
    for (int t = tid; t < T; t += 256) s += __expf(mr[t] - m);
    red[tid] = s;
    __syncthreads();
    for (int o = 128; o; o >>= 1) {
        if (tid < o) red[tid] += red[tid + o];
        __syncthreads();
    }
    float binv = 1.0f / red[0];
    if (tid < 64) wbt[tid] = __expf(mr[tc * 64 + tid] - m) * binv;
    __syncthreads();

    int dd = tid * 4;
    float acc0 = 0.f, acc1 = 0.f, acc2 = 0.f, acc3 = 0.f;
#pragma unroll 4
    for (int i = 0; i < 64; ++i) {
        int t = tc * 64 + i;
        uint2 v = *(const uint2*)&hbf[((size_t)(b << 10) + t) * H + dd];
        const ushort_t* us = (const ushort_t*)&v;
        float wv = wbt[i];
        acc0 += wv * bf2f(us[0]);
        acc1 += wv * bf2f(us[1]);
        acc2 += wv * bf2f(us[2]);
        acc3 += wv * bf2f(us[3]);
    }
    size_t pb = (((size_t)b * 16 + tc) << 10) + dd;
    *(float4*)&part[pb] = make_float4(acc0, acc1, acc2, acc3);
}

// ---------------------------------------------------------------------------
// k_gemm2g: prologue reduces (pcm,pcs)->cmax/cinv (all j) and qpart->q2c
// (its 128 d) into LDS; stages P with on-the-fly softmax normalize;
// c2q = P @ u via MFMA (A=uT rows=d, B=P cols=t); fused float4 G writer.
// XCD-pinned per batch. grid 2048, 256 thr.
// ---------------------------------------------------------------------------
__global__ __launch_bounds__(256) void k_gemm2g(const ushort_t* __restrict__ Sb,
                                                const ushort_t* __restrict__ uT,
                                                const ushort_t* __restrict__ hbf,
                                                const float* __restrict__ pcm,
                                                const float* __restrict__ pcs,
                                                const float* __restrict__ qpart,
                                                float* __restrict__ G) {
    const int lid = blockIdx.x;
    const int seq = lid >> 3;
    const int b = (lid & 7) * 4 + (seq >> 6);
    const int inner = seq & 63;
    const int d0 = (inner >> 3) * 128;
    const int t0 = (inner & 7) * 128;
    __shared__ ushort_t Ps[128 * 64];
    __shared__ ushort_t Us[128 * 64];
    __shared__ float cmaxs[128], cinvs[128], q2cs[128];
    const int tid = threadIdx.x;
    const int lane = tid & 63, wid = tid >> 6;
    const int wd = wid >> 1, wt = wid & 1;

    // prologue: column stats (tid<128) and q2c reduction (tid>=128)
    if (tid < 128) {
        int col = (b << 7) + tid;
        float m = -INFINITY, s = 0.0f;
#pragma unroll
        for (int r = 0; r < 8; ++r) {
            float m2 = pcm[col * 8 + r], s2 = pcs[col * 8 + r];
            float nm = fmaxf(m, m2);
            s = s * __expf(m - nm) + s2 * __expf(m2 - nm);
            m = nm;
        }
        cmaxs[tid] = m;
        cinvs[tid] = 1.0f / s;
    } else {
        int d = d0 + tid - 128;
        float a = 0.0f;
#pragma unroll
        for (int tc = 0; tc < 16; ++tc)
            a += qpart[(((size_t)b * 16 + tc) << 10) + d];
        q2cs[tid - 128] = a;
    }
    __syncthreads();

    f32x4 acc[4][4] = {};
    for (int j0 = 0; j0 < J; j0 += 64) {
#pragma unroll
        for (int w = 0; w < 4; ++w) {
            int row = w * 32 + (tid >> 3);
            int u_ = tid & 7;
            int cb = (u_ ^ ((tid >> 3) & 7)) << 4;
            // P with fused softmax normalize (elements are j = j0+cb/2+i)
            uint4 va = *(const uint4*)((const char*)Sb +
                       (((size_t)(b << 10) + t0 + row) * J + j0) * 2 + cb);
            int jb = j0 + (cb >> 1);
            union { ushort_t us[8]; uint4 v; } pp;
            pp.v = va;
#pragma unroll
            for (int i = 0; i < 8; ++i)
                pp.us[i] = f2bf(__expf(bf2f(pp.us[i]) - cmaxs[jb + i]) * cinvs[jb + i]);
            *(uint4*)&Ps[row * 64 + (u_ << 3)] = pp.v;
            uint4 vb = *(const uint4*)((const char*)uT +
                       (((size_t)(b << 10) + d0 + row) * J + j0) * 2 + cb);
            *(uint4*)&Us[row * 64 + (u_ << 3)] = vb;
        }
        __syncthreads();
#pragma unroll
        for (int ks = 0; ks < 2; ++ks) {
            bf16x8 af[4], bfr[4];
            int cbyte = ks * 64 + ((lane >> 4) << 4);
#pragma unroll
            for (int mi = 0; mi < 4; ++mi) {
                int row = wd * 64 + mi * 16 + (lane & 15);
                af[mi] = *(const bf16x8*)&Us[row * 64 + ((cbyte ^ ((row & 7) << 4)) >> 1)];
            }
#pragma unroll
            for (int nj = 0; nj < 4; ++nj) {
                int row = wt * 64 + nj * 16 + (lane & 15);
                bfr[nj] = *(const bf16x8*)&Ps[row * 64 + ((cbyte ^ ((row & 7) << 4)) >> 1)];
            }
#pragma unroll
            for (int mi = 0; mi < 4; ++mi)
#pragma unroll
                for (int nj = 0; nj < 4; ++nj)
                    acc[mi][nj] = __builtin_amdgcn_mfma_f32_16x16x32_bf16(
                        af[mi], bfr[nj], acc[mi][nj], 0, 0, 0);
        }
        __syncthreads();
    }

    // epilogue: lane owns 4 consecutive d; float4 stores for all G sections
    const int lane15 = lane & 15, lq = lane >> 4;
#pragma unroll
    for (int mi = 0; mi < 4; ++mi) {
        int dloc = wd * 64 + mi * 16 + lq * 4;
        int drow = d0 + dloc;
        float4 qv = *(const float4*)&q2cs[dloc];
#pragma unroll
        for (int nj = 0; nj < 4; ++nj) {
            int tcol = t0 + wt * 64 + nj * 16 + lane15;
            size_t rowoff = ((size_t)(b << 10) + tcol);
            uint2 h2 = *(const uint2*)&hbf[rowoff * H + drow];
            const ushort_t* hu = (const ushort_t*)&h2;
            float4 hv = make_float4(bf2f(hu[0]), bf2f(hu[1]), bf2f(hu[2]), bf2f(hu[3]));
            f32x4 a = acc[mi][nj];
            float4 cv = make_float4(a[0], a[1], a[2], a[3]);
            size_t gp = rowoff * (4 * H) + drow;
            *(float4*)&G[gp] = hv;
            *(float4*)&G[gp + H] = cv;
            *(float4*)&G[gp + 2 * H] = make_float4(hv.x * cv.x, hv.y * cv.y,
                                                   hv.z * cv.z, hv.w * cv.w);
            *(float4*)&G[gp + 3 * H] = make_float4(hv.x * qv.x, hv.y * qv.y,
                                                   hv.z * qv.z, hv.w * qv.w);
        }
    }
}

extern "C" void kernel_launch(void* const* d_in, const int* in_sizes, int n_in,
                              void* d_out, int out_size, void* d_ws, size_t ws_size,
                              hipStream_t stream) {
    const float* h = (const float*)d_in[0];
    const float* u = (const float*)d_in[1];
    const float* w = (const float*)d_in[2];
    const float* bb = (const float*)d_in[3];
    float* G = (float*)d_out;

    char* p = (char*)d_ws;
    ushort_t* Sb = (ushort_t*)p; p += (size_t)B * T * J * 2;
    ushort_t* u2 = (ushort_t*)p; p += (size_t)B * J * H * 2;
    ushort_t* uT = (ushort_t*)p; p += (size_t)B * H * J * 2;
    ushort_t* hbf = (ushort_t*)p; p += (size_t)B * T * H * 2;
    float* pdot = (float*)p; p += (size_t)B * J * 16 * 4;
    float* suB = (float*)p; p += B * J * 4;
    float* pcm = (float*)p; p += B * J * 8 * 4;
    float* pcs = (float*)p; p += B * J * 8 * 4;
    float* Mrow = (float*)p; p += B * T * 4;
    float* qpart = (float*)p;  // B*16*H*4

    k_uprep<<<dim3(H / 64, J / 64, B), 256, 0, stream>>>(u, w, u2, uT, pdot);
    k_sured<<<dim3(B * J / 256), 256, 0, stream>>>(pdot, bb, suB);
    k_gemm1<<<dim3(256), 512, 0, stream>>>(h, u2, suB, Sb, hbf, Mrow, pcm, pcs);
    k_q2c_part<<<dim3(16, B), 256, 0, stream>>>(hbf, Mrow, qpart);
    k_gemm2g<<<dim3(2048), 256, 0, stream>>>(Sb, uT, hbf, pcm, pcs, qpart, G);
}